// Round 1
// baseline (5756.419 us; speedup 1.0000x reference)
//
#include <hip/hip_runtime.h>
#include <hip/hip_bf16.h>

#pragma clang fp contract(off)

// ---------- numeric helpers (rounding-faithful to XLA reference) ----------
__device__ __forceinline__ float lrelu(float v) { return v >= 0.0f ? v : 0.1f * v; }

// sum of squares, per-op rounding, NO fma (matches mul-then-reduce HLO)
__device__ __forceinline__ float sumsq3(float x, float y, float z) {
    return ((x * x) + (y * y)) + (z * z);
}

// dot product as fma chain from zero (matches Eigen/gemm accumulation)
__device__ __forceinline__ float dot3fma(float ax, float ay, float az,
                                         float bx, float by, float bz) {
    float d = ax * bx;                 // == fmaf(ax,bx,0)
    d = __builtin_fmaf(ay, by, d);
    d = __builtin_fmaf(az, bz, d);
    return d;
}

// ---------- kernel 1: pre-MLP  x0 = lrelu(g*(Wpre@feat)+b), point-major out ----------
__global__ void k_pre(const float* __restrict__ feat, const float* __restrict__ W,
                      const float* __restrict__ g, const float* __restrict__ bb,
                      float* __restrict__ x0) {
    int p = blockIdx.x * blockDim.x + threadIdx.x;  // 0 .. 2*8192-1
    if (p >= 2 * 8192) return;
    const float* f = feat + (size_t)p * 6;
    float fv[6];
#pragma unroll
    for (int c = 0; c < 6; ++c) fv[c] = f[c];
    float* out = x0 + (size_t)p * 64;
    for (int o = 0; o < 64; ++o) {
        float s = 0.0f;
#pragma unroll
        for (int c = 0; c < 6; ++c) s = __builtin_fmaf(W[o * 6 + c], fv[c], s);
        float v = s * g[o];
        v = v + bb[o];
        out[o] = lrelu(v);
    }
}

// ---------- kernel 2: brute-force KNN (top-16 by (d2, idx) lexicographic) ----------
template <int TS>
__global__ void k_knn(const float* __restrict__ xyz, int* __restrict__ out_idx, int Npts) {
    __shared__ float sx[TS], sy[TS], sz[TS], sn[TS];
    int b = blockIdx.y;
    int q = blockIdx.x * blockDim.x + threadIdx.x;
    const float* X = xyz + (size_t)b * Npts * 3;
    bool act = q < Npts;
    float qx = 0, qy = 0, qz = 0, qn = 0;
    if (act) {
        qx = X[q * 3]; qy = X[q * 3 + 1]; qz = X[q * 3 + 2];
        qn = sumsq3(qx, qy, qz);
    }
    float dist[16]; int idx[16];
#pragma unroll
    for (int j = 0; j < 16; ++j) { dist[j] = INFINITY; idx[j] = 0x7fffffff; }

    for (int t0 = 0; t0 < Npts; t0 += TS) {
        __syncthreads();
        for (int j = threadIdx.x; j < TS; j += blockDim.x) {
            int i = t0 + j;
            float px = X[i * 3], py = X[i * 3 + 1], pz = X[i * 3 + 2];
            sx[j] = px; sy[j] = py; sz[j] = pz; sn[j] = sumsq3(px, py, pz);
        }
        __syncthreads();
        if (act) {
            for (int j = 0; j < TS; ++j) {
                float d = (qn + sn[j]) - 2.0f * dot3fma(qx, qy, qz, sx[j], sy[j], sz[j]);
                if (d < dist[15]) {      // strict: equal-d later index never displaces
                    float cd = d; int ci = t0 + j;
#pragma unroll
                    for (int u = 0; u < 16; ++u) {   // static-index bubble insert
                        bool sw = cd < dist[u];
                        float td = sw ? dist[u] : cd; int ti = sw ? idx[u] : ci;
                        dist[u] = sw ? cd : dist[u];  idx[u] = sw ? ci : idx[u];
                        cd = td; ci = ti;
                    }
                }
            }
        }
    }
    if (act) {
        int* o = out_idx + ((size_t)b * Npts + q) * 16;
#pragma unroll
        for (int j = 0; j < 16; ++j) o[j] = idx[j];
    }
}

// ---------- kernel 3: gather selected points (xyz + features) ----------
template <int C>
__global__ void k_gather(const float* __restrict__ src_xyz, const float* __restrict__ src_feat,
                         const int* __restrict__ sel, float* __restrict__ dst_xyz,
                         float* __restrict__ dst_feat, int M, int Nsrc) {
    int b = blockIdx.y, m = blockIdx.x;
    int s = sel[(size_t)b * M + m];
    const float* fx = src_xyz + ((size_t)b * Nsrc + s) * 3;
    const float* ff = src_feat + ((size_t)b * Nsrc + s) * C;
    float* dx = dst_xyz + ((size_t)b * M + m) * 3;
    float* df = dst_feat + ((size_t)b * M + m) * C;
    if (threadIdx.x < 3) dx[threadIdx.x] = fx[threadIdx.x];
    for (int c = threadIdx.x; c < C; c += blockDim.x) df[c] = ff[c];
}

// ---------- kernel 4: LFA block (rel-encode -> Wm -> attention -> pool -> Wp) ----------
template <int CIN, int COUT>
__global__ void k_lfa(const float* __restrict__ xyz, const float* __restrict__ feat,
                      const int* __restrict__ knn,
                      const float* __restrict__ Wm, const float* __restrict__ gm, const float* __restrict__ bm,
                      const float* __restrict__ Ws,
                      const float* __restrict__ Wp, const float* __restrict__ gp, const float* __restrict__ bp,
                      float* __restrict__ outf, int Npts) {
    constexpr int CR = CIN + 10;
    __shared__ float xin[CR * 16];
    __shared__ float xmid[COUT * 16];
    __shared__ float pooled[COUT];
    int b = blockIdx.y, n = blockIdx.x, tid = threadIdx.x;
    const float* X = xyz + (size_t)b * Npts * 3;
    const float* F = feat + (size_t)b * Npts * CIN;
    const int* nb = knn + ((size_t)b * Npts + n) * 16;
    float cx = X[n * 3], cy = X[n * 3 + 1], cz = X[n * 3 + 2];

    if (tid < 16) {  // rel channels: [diff(3), dist(1), center(3), neigh(3)]
        int k = tid;
        int j = nb[k];
        float nx = X[j * 3], ny = X[j * 3 + 1], nz = X[j * 3 + 2];
        float dx = cx - nx, dy = cy - ny, dz = cz - nz;
        float dn = sqrtf(sumsq3(dx, dy, dz));
        xin[(CIN + 0) * 16 + k] = dx; xin[(CIN + 1) * 16 + k] = dy; xin[(CIN + 2) * 16 + k] = dz;
        xin[(CIN + 3) * 16 + k] = dn;
        xin[(CIN + 4) * 16 + k] = cx; xin[(CIN + 5) * 16 + k] = cy; xin[(CIN + 6) * 16 + k] = cz;
        xin[(CIN + 7) * 16 + k] = nx; xin[(CIN + 8) * 16 + k] = ny; xin[(CIN + 9) * 16 + k] = nz;
    }
    {   // neighbor features -> xin[c][k]
        int k = tid & 15;
        int j = nb[k];
        const float* fr = F + (size_t)j * CIN;
        for (int c = tid >> 4; c < CIN; c += 16) xin[c * 16 + k] = fr[c];
    }
    __syncthreads();

    constexpr int ENT = COUT * 16;
    for (int e = tid; e < ENT; e += 256) {   // x = bn_act(Wm @ xin)
        int o = e >> 4, k = e & 15;
        const float* wr = Wm + (size_t)o * CR;
        float s = 0.0f;
        for (int c = 0; c < CR; ++c) s = __builtin_fmaf(wr[c], xin[c * 16 + k], s);
        float v = s * gm[o]; v = v + bm[o];
        xmid[e] = lrelu(v);
    }
    __syncthreads();

    for (int e = tid; e < ENT; e += 256) {   // scores, softmax over k, pool
        int o = e >> 4, k = e & 15;
        const float* wr = Ws + (size_t)o * COUT;
        float s = 0.0f;
        for (int c = 0; c < COUT; ++c) s = __builtin_fmaf(wr[c], xmid[c * 16 + k], s);
        float m = s;
        m = fmaxf(m, __shfl_xor(m, 1));
        m = fmaxf(m, __shfl_xor(m, 2));
        m = fmaxf(m, __shfl_xor(m, 4));
        m = fmaxf(m, __shfl_xor(m, 8));
        float e_ = expf(s - m);
        float se = e_;
        se += __shfl_xor(se, 1); se += __shfl_xor(se, 2);
        se += __shfl_xor(se, 4); se += __shfl_xor(se, 8);
        float a = e_ / se;
        float wv = xmid[o * 16 + k] * a;
        wv += __shfl_xor(wv, 1); wv += __shfl_xor(wv, 2);
        wv += __shfl_xor(wv, 4); wv += __shfl_xor(wv, 8);
        if (k == 0) pooled[o] = wv;
    }
    __syncthreads();

    for (int o = tid; o < COUT; o += 256) {  // out = bn_act(Wp @ pooled)
        const float* wr = Wp + (size_t)o * COUT;
        float s = 0.0f;
        for (int c = 0; c < COUT; ++c) s = __builtin_fmaf(wr[c], pooled[c], s);
        float v = s * gp[o]; v = v + bp[o];
        outf[((size_t)b * Npts + n) * COUT + o] = lrelu(v);
    }
}

// ---------- kernel 5: nearest-neighbor index (argmin d2, ties -> lowest idx) ----------
template <int TS>
__global__ void k_nn(const float* __restrict__ tgt, const float* __restrict__ src,
                     int* __restrict__ nn, int Mt, int Ms) {
    __shared__ float sx[TS], sy[TS], sz[TS], sn[TS];
    int b = blockIdx.y;
    int q = blockIdx.x * blockDim.x + threadIdx.x;
    const float* T = tgt + (size_t)b * Mt * 3;
    const float* S = src + (size_t)b * Ms * 3;
    bool act = q < Mt;
    float qx = 0, qy = 0, qz = 0, qn = 0;
    if (act) {
        qx = T[q * 3]; qy = T[q * 3 + 1]; qz = T[q * 3 + 2];
        qn = sumsq3(qx, qy, qz);
    }
    float bd = INFINITY; int bi = 0;
    for (int t0 = 0; t0 < Ms; t0 += TS) {
        __syncthreads();
        for (int j = threadIdx.x; j < TS; j += blockDim.x) {
            int i = t0 + j;
            float px = S[i * 3], py = S[i * 3 + 1], pz = S[i * 3 + 2];
            sx[j] = px; sy[j] = py; sz[j] = pz; sn[j] = sumsq3(px, py, pz);
        }
        __syncthreads();
        if (act) {
            for (int j = 0; j < TS; ++j) {
                float d = (qn + sn[j]) - 2.0f * dot3fma(qx, qy, qz, sx[j], sy[j], sz[j]);
                if (d < bd) { bd = d; bi = t0 + j; }   // strict < : ties keep lowest index
            }
        }
    }
    if (act) nn[(size_t)b * Mt + q] = bi;
}

// ---------- kernel 6: up-sample (gather NN feat) + concat skip + dense + bn_act ----------
template <int CSRC, int CSKIP, int COUT>
__global__ void k_up(const float* __restrict__ srcf, const float* __restrict__ skipf,
                     const int* __restrict__ nn,
                     const float* __restrict__ W, const float* __restrict__ g, const float* __restrict__ bb,
                     float* __restrict__ outf, int Mt, int Ms) {
    __shared__ float fin[CSRC + CSKIP];
    int b = blockIdx.y, n = blockIdx.x, tid = threadIdx.x;
    int j = nn[(size_t)b * Mt + n];
    const float* fs = srcf + ((size_t)b * Ms + j) * CSRC;
    const float* fk = skipf + ((size_t)b * Mt + n) * CSKIP;
    for (int c = tid; c < CSRC; c += blockDim.x) fin[c] = fs[c];
    for (int c = tid; c < CSKIP; c += blockDim.x) fin[CSRC + c] = fk[c];
    __syncthreads();
    for (int o = tid; o < COUT; o += blockDim.x) {
        const float* wr = W + (size_t)o * (CSRC + CSKIP);
        float s = 0.0f;
        for (int c = 0; c < CSRC + CSKIP; ++c) s = __builtin_fmaf(wr[c], fin[c], s);
        float v = s * g[o]; v = v + bb[o];
        outf[((size_t)b * Mt + n) * COUT + o] = lrelu(v);
    }
}

// ---------- kernel 7: final up-sample + concat + Wu1 + head (Wh1, Wh2) fused ----------
__global__ void k_u1head(const float* __restrict__ srcf, const float* __restrict__ skipf,
                         const int* __restrict__ nn,
                         const float* __restrict__ Wu1, const float* __restrict__ gu1, const float* __restrict__ bu1,
                         const float* __restrict__ Wh1, const float* __restrict__ bh1,
                         const float* __restrict__ Wh2, const float* __restrict__ bh2,
                         float* __restrict__ out, int Mt, int Ms) {
    __shared__ float fin[192];
    __shared__ float d1[64];
    __shared__ float h[64];
    int b = blockIdx.y, n = blockIdx.x, tid = threadIdx.x;  // 64 threads
    int j = nn[(size_t)b * Mt + n];
    const float* fs = srcf + ((size_t)b * Ms + j) * 128;
    const float* fk = skipf + ((size_t)b * Mt + n) * 64;
    for (int c = tid; c < 128; c += 64) fin[c] = fs[c];
    fin[128 + tid] = fk[tid];
    __syncthreads();
    {
        const float* wr = Wu1 + (size_t)tid * 192;
        float s = 0.0f;
        for (int c = 0; c < 192; ++c) s = __builtin_fmaf(wr[c], fin[c], s);
        float v = s * gu1[tid]; v = v + bu1[tid];
        d1[tid] = lrelu(v);
    }
    __syncthreads();
    {
        const float* wr = Wh1 + (size_t)tid * 64;
        float s = 0.0f;
        for (int c = 0; c < 64; ++c) s = __builtin_fmaf(wr[c], d1[c], s);
        float v = s + bh1[tid];
        h[tid] = lrelu(v);
    }
    __syncthreads();
    if (tid < 13) {
        const float* wr = Wh2 + (size_t)tid * 64;
        float s = 0.0f;
        for (int c = 0; c < 64; ++c) s = __builtin_fmaf(wr[c], h[c], s);
        out[((size_t)b * Mt + n) * 13 + tid] = s + bh2[tid];
    }
}

// ---------- launch ----------
extern "C" void kernel_launch(void* const* d_in, const int* in_sizes, int n_in,
                              void* d_out, int out_size, void* d_ws, size_t ws_size,
                              hipStream_t stream) {
    const float* xyz  = (const float*)d_in[0];
    const float* feat = (const float*)d_in[1];
    const int*   sel1 = (const int*)d_in[2];
    const int*   sel2 = (const int*)d_in[3];
    const float* Wpre = (const float*)d_in[4];
    const float* gpre = (const float*)d_in[5];
    const float* bpre = (const float*)d_in[6];
    const float* W1m  = (const float*)d_in[7];
    const float* g1m  = (const float*)d_in[8];
    const float* b1m  = (const float*)d_in[9];
    const float* W1s  = (const float*)d_in[10];
    const float* W1p  = (const float*)d_in[11];
    const float* g1p  = (const float*)d_in[12];
    const float* b1p  = (const float*)d_in[13];
    const float* W2m  = (const float*)d_in[14];
    const float* g2m  = (const float*)d_in[15];
    const float* b2m  = (const float*)d_in[16];
    const float* W2s  = (const float*)d_in[17];
    const float* W2p  = (const float*)d_in[18];
    const float* g2p  = (const float*)d_in[19];
    const float* b2p  = (const float*)d_in[20];
    const float* W3m  = (const float*)d_in[21];
    const float* g3m  = (const float*)d_in[22];
    const float* b3m  = (const float*)d_in[23];
    const float* W3s  = (const float*)d_in[24];
    const float* W3p  = (const float*)d_in[25];
    const float* g3p  = (const float*)d_in[26];
    const float* b3p  = (const float*)d_in[27];
    const float* Wu2  = (const float*)d_in[28];
    const float* gu2  = (const float*)d_in[29];
    const float* bu2  = (const float*)d_in[30];
    const float* Wu1  = (const float*)d_in[31];
    const float* gu1  = (const float*)d_in[32];
    const float* bu1  = (const float*)d_in[33];
    const float* Wh1  = (const float*)d_in[34];
    const float* bh1  = (const float*)d_in[35];
    const float* Wh2  = (const float*)d_in[36];
    const float* bh2  = (const float*)d_in[37];
    float* out = (float*)d_out;

    char* w = (char*)d_ws;
    auto alloc = [&](size_t n) { char* p = w; w += (n + 255) & ~(size_t)255; return p; };
    float* x0   = (float*)alloc((size_t)2 * 8192 * 64 * 4);
    float* x1   = (float*)alloc((size_t)2 * 8192 * 64 * 4);
    float* f1   = (float*)alloc((size_t)2 * 4096 * 64 * 4);
    float* x2   = (float*)alloc((size_t)2 * 4096 * 128 * 4);
    float* f2   = (float*)alloc((size_t)2 * 2048 * 128 * 4);
    float* x3   = (float*)alloc((size_t)2 * 2048 * 256 * 4);
    float* d2f  = (float*)alloc((size_t)2 * 4096 * 128 * 4);
    float* xyz1 = (float*)alloc((size_t)2 * 4096 * 3 * 4);
    float* xyz2 = (float*)alloc((size_t)2 * 2048 * 3 * 4);
    int* n0   = (int*)alloc((size_t)2 * 8192 * 16 * 4);
    int* n1   = (int*)alloc((size_t)2 * 4096 * 16 * 4);
    int* n2   = (int*)alloc((size_t)2 * 2048 * 16 * 4);
    int* nnu2 = (int*)alloc((size_t)2 * 4096 * 4);
    int* nnu1 = (int*)alloc((size_t)2 * 8192 * 4);

    k_pre<<<128, 128, 0, stream>>>(feat, Wpre, gpre, bpre, x0);
    k_knn<256><<<dim3(128, 2), 64, 0, stream>>>(xyz, n0, 8192);
    k_lfa<64, 64><<<dim3(8192, 2), 256, 0, stream>>>(xyz, x0, n0, W1m, g1m, b1m, W1s,
                                                     W1p, g1p, b1p, x1, 8192);
    k_gather<64><<<dim3(4096, 2), 64, 0, stream>>>(xyz, x1, sel1, xyz1, f1, 4096, 8192);
    k_knn<256><<<dim3(64, 2), 64, 0, stream>>>(xyz1, n1, 4096);
    k_lfa<64, 128><<<dim3(4096, 2), 256, 0, stream>>>(xyz1, f1, n1, W2m, g2m, b2m, W2s,
                                                      W2p, g2p, b2p, x2, 4096);
    k_gather<128><<<dim3(2048, 2), 64, 0, stream>>>(xyz1, x2, sel2, xyz2, f2, 2048, 4096);
    k_knn<256><<<dim3(32, 2), 64, 0, stream>>>(xyz2, n2, 2048);
    k_lfa<128, 256><<<dim3(2048, 2), 256, 0, stream>>>(xyz2, f2, n2, W3m, g3m, b3m, W3s,
                                                       W3p, g3p, b3p, x3, 2048);
    k_nn<256><<<dim3(64, 2), 64, 0, stream>>>(xyz1, xyz2, nnu2, 4096, 2048);
    k_up<256, 128, 128><<<dim3(4096, 2), 128, 0, stream>>>(x3, x2, nnu2, Wu2, gu2, bu2,
                                                           d2f, 4096, 2048);
    k_nn<256><<<dim3(128, 2), 64, 0, stream>>>(xyz, xyz1, nnu1, 8192, 4096);
    k_u1head<<<dim3(8192, 2), 64, 0, stream>>>(d2f, x1, nnu1, Wu1, gu1, bu1, Wh1, bh1,
                                               Wh2, bh2, out, 8192, 4096);
}

// Round 2
// 4213.856 us; speedup vs baseline: 1.3661x; 1.3661x over previous
//
#include <hip/hip_runtime.h>
#include <hip/hip_bf16.h>

#pragma clang fp contract(off)

// ---------- numeric helpers (rounding-faithful to reference) ----------
__device__ __forceinline__ float lrelu(float v) { return v >= 0.0f ? v : 0.1f * v; }

__device__ __forceinline__ float sumsq3(float x, float y, float z) {
    return ((x * x) + (y * y)) + (z * z);
}

__device__ __forceinline__ float dot3fma(float ax, float ay, float az,
                                         float bx, float by, float bz) {
    float d = ax * bx;
    d = __builtin_fmaf(ay, by, d);
    d = __builtin_fmaf(az, bz, d);
    return d;
}

// ---------- kernel 1: pre-MLP ----------
__global__ void k_pre(const float* __restrict__ feat, const float* __restrict__ W,
                      const float* __restrict__ g, const float* __restrict__ bb,
                      float* __restrict__ x0) {
    int p = blockIdx.x * blockDim.x + threadIdx.x;
    if (p >= 2 * 8192) return;
    const float* f = feat + (size_t)p * 6;
    float fv[6];
#pragma unroll
    for (int c = 0; c < 6; ++c) fv[c] = f[c];
    float* out = x0 + (size_t)p * 64;
    for (int o = 0; o < 64; ++o) {
        float s = 0.0f;
#pragma unroll
        for (int c = 0; c < 6; ++c) s = __builtin_fmaf(W[o * 6 + c], fv[c], s);
        float v = s * g[o];
        v = v + bb[o];
        out[o] = lrelu(v);
    }
}

// ---------- kernel 2: brute-force KNN (top-16 by (d2, idx)) ----------
template <int TS>
__global__ void k_knn(const float* __restrict__ xyz, int* __restrict__ out_idx, int Npts) {
    __shared__ float sx[TS], sy[TS], sz[TS], sn[TS];
    int b = blockIdx.y;
    int q = blockIdx.x * blockDim.x + threadIdx.x;
    const float* X = xyz + (size_t)b * Npts * 3;
    bool act = q < Npts;
    float qx = 0, qy = 0, qz = 0, qn = 0;
    if (act) {
        qx = X[q * 3]; qy = X[q * 3 + 1]; qz = X[q * 3 + 2];
        qn = sumsq3(qx, qy, qz);
    }
    float dist[16]; int idx[16];
#pragma unroll
    for (int j = 0; j < 16; ++j) { dist[j] = INFINITY; idx[j] = 0x7fffffff; }

    for (int t0 = 0; t0 < Npts; t0 += TS) {
        __syncthreads();
        for (int j = threadIdx.x; j < TS; j += blockDim.x) {
            int i = t0 + j;
            float px = X[i * 3], py = X[i * 3 + 1], pz = X[i * 3 + 2];
            sx[j] = px; sy[j] = py; sz[j] = pz; sn[j] = sumsq3(px, py, pz);
        }
        __syncthreads();
        if (act) {
            for (int j = 0; j < TS; ++j) {
                float d = (qn + sn[j]) - 2.0f * dot3fma(qx, qy, qz, sx[j], sy[j], sz[j]);
                if (d < dist[15]) {
                    float cd = d; int ci = t0 + j;
#pragma unroll
                    for (int u = 0; u < 16; ++u) {
                        bool sw = cd < dist[u];
                        float td = sw ? dist[u] : cd; int ti = sw ? idx[u] : ci;
                        dist[u] = sw ? cd : dist[u];  idx[u] = sw ? ci : idx[u];
                        cd = td; ci = ti;
                    }
                }
            }
        }
    }
    if (act) {
        int* o = out_idx + ((size_t)b * Npts + q) * 16;
#pragma unroll
        for (int j = 0; j < 16; ++j) o[j] = idx[j];
    }
}

// ---------- kernel 3: gather selected points ----------
template <int C>
__global__ void k_gather(const float* __restrict__ src_xyz, const float* __restrict__ src_feat,
                         const int* __restrict__ sel, float* __restrict__ dst_xyz,
                         float* __restrict__ dst_feat, int M, int Nsrc) {
    int b = blockIdx.y, m = blockIdx.x;
    int s = sel[(size_t)b * M + m];
    const float* fx = src_xyz + ((size_t)b * Nsrc + s) * 3;
    const float* ff = src_feat + ((size_t)b * Nsrc + s) * C;
    float* dx = dst_xyz + ((size_t)b * M + m) * 3;
    float* df = dst_feat + ((size_t)b * M + m) * C;
    if (threadIdx.x < 3) dx[threadIdx.x] = fx[threadIdx.x];
    for (int c = threadIdx.x; c < C; c += blockDim.x) df[c] = ff[c];
}

// ---------- kernel 4: encode — build XIN[CR][colsC] for a column chunk ----------
// row order: [neigh_feat(CIN)] then [dx,dy,dz,dist,cx,cy,cz,nx,ny,nz]
template <int CIN>
__global__ void k_encode(const float* __restrict__ xyz, const float* __restrict__ feat,
                         const int* __restrict__ kn, float* __restrict__ XIN,
                         int Npts, int colsC, int j0) {
    int jl = blockIdx.x * 256 + threadIdx.x;
    if (jl >= colsC) return;
    int jg = j0 + jl;
    int p = jg >> 4;
    int b = p / Npts, n = p - b * Npts;
    int nbr = kn[jg];
    const float* X = xyz + (size_t)b * Npts * 3;
    float cx = X[n * 3 + 0], cy = X[n * 3 + 1], cz = X[n * 3 + 2];
    float nx = X[nbr * 3 + 0], ny = X[nbr * 3 + 1], nz = X[nbr * 3 + 2];
    const float* fr = feat + ((size_t)b * Npts + nbr) * CIN;
    for (int c = 0; c < CIN; ++c) XIN[(size_t)c * colsC + jl] = fr[c];
    float dx = cx - nx, dy = cy - ny, dz = cz - nz;
    float dn = sqrtf(sumsq3(dx, dy, dz));
    float* Xr = XIN + (size_t)CIN * colsC + jl;
    size_t st = (size_t)colsC;
    Xr[0 * st] = dx; Xr[1 * st] = dy; Xr[2 * st] = dz; Xr[3 * st] = dn;
    Xr[4 * st] = cx; Xr[5 * st] = cy; Xr[6 * st] = cz;
    Xr[7 * st] = nx; Xr[8 * st] = ny; Xr[9 * st] = nz;
}

// ---------- kernel 5: register-tiled f32 GEMM with fused epilogues ----------
// C[M][cols] = A[M][K] @ B[K][cols]; fma chain ascending in c (k-padded with exact zeros).
// EPI: 1 = bnact row-major store; 2 = bnact transposed (point-major) store;
//      3 = softmax over 16-col groups (even/odd lane pair) + attention pool -> pooled.
template <int BM, int BN, int BK, int EPI>
__launch_bounds__(256)
__global__ void k_gemm(const float* __restrict__ A, const float* __restrict__ B,
                       const float* __restrict__ g, const float* __restrict__ bb,
                       float* __restrict__ C, float* __restrict__ pooled,
                       int M, int K, int cols, int pstride) {
    static_assert(BN == 128 && BK == 16, "layout assumptions");
    constexpr int RT = BM / 16, CT = BN / 16;   // per-thread tile RT x CT
    __shared__ float sA[BK][BM + 4];
    __shared__ float sB[BK][BN];
    int tid = threadIdx.x;
    int tx = tid & 15, ty = tid >> 4;
    int jb = blockIdx.x * BN;
    int om = blockIdx.y * BM;

    float acc[RT][CT];
#pragma unroll
    for (int r = 0; r < RT; ++r)
#pragma unroll
        for (int c = 0; c < CT; ++c) acc[r][c] = 0.0f;

    for (int ck = 0; ck < K; ck += BK) {
        {   // A tile: [BM][BK] -> sA[c][r] (transposed)
            int c = tid & 15;
            int r0 = tid >> 4;
            int cc = ck + c;
            for (int rr = r0; rr < BM; rr += 16) {
                float v = 0.0f;
                if (cc < K) v = A[(size_t)(om + rr) * K + cc];
                sA[c][rr] = v;
            }
        }
        {   // B tile: [BK][BN]
            int jj = tid & 127;
            int c0 = tid >> 7;
            for (int cp = c0; cp < BK; cp += 2) {
                float v = 0.0f;
                if (ck + cp < K) v = B[(size_t)(ck + cp) * cols + jb + jj];
                sB[cp][jj] = v;
            }
        }
        __syncthreads();
#pragma unroll
        for (int c = 0; c < BK; ++c) {
            float a[RT], bv[CT];
            *reinterpret_cast<float4*>(&a[0]) =
                *reinterpret_cast<const float4*>(&sA[c][ty * RT]);
            if (RT == 8)
                *reinterpret_cast<float4*>(&a[4]) =
                    *reinterpret_cast<const float4*>(&sA[c][ty * RT + 4]);
            *reinterpret_cast<float4*>(&bv[0]) =
                *reinterpret_cast<const float4*>(&sB[c][tx * CT]);
            *reinterpret_cast<float4*>(&bv[4]) =
                *reinterpret_cast<const float4*>(&sB[c][tx * CT + 4]);
#pragma unroll
            for (int r = 0; r < RT; ++r)
#pragma unroll
                for (int cc = 0; cc < CT; ++cc)
                    acc[r][cc] = __builtin_fmaf(a[r], bv[cc], acc[r][cc]);
        }
        __syncthreads();
    }

    if (EPI == 1) {
#pragma unroll
        for (int r = 0; r < RT; ++r) {
            int o = om + ty * RT + r;
            float gg = g[o], bbv = bb[o];
#pragma unroll
            for (int cc = 0; cc < CT; ++cc) {
                float v = acc[r][cc] * gg;
                v = v + bbv;
                C[(size_t)o * cols + jb + tx * CT + cc] = lrelu(v);
            }
        }
    } else if (EPI == 2) {
#pragma unroll
        for (int r = 0; r < RT; ++r) {
            int o = om + ty * RT + r;
            float gg = g[o], bbv = bb[o];
#pragma unroll
            for (int cc = 0; cc < CT; ++cc) {
                float v = acc[r][cc] * gg;
                v = v + bbv;
                C[(size_t)(jb + tx * CT + cc) * M + o] = lrelu(v);
            }
        }
    } else if (EPI == 3) {
        // each 16-col point group spans lanes (tx even, tx odd) of the same wave
#pragma unroll
        for (int r = 0; r < RT; ++r) {
            int o = om + ty * RT + r;
            float m = acc[r][0];
#pragma unroll
            for (int cc = 1; cc < CT; ++cc) m = fmaxf(m, acc[r][cc]);
            m = fmaxf(m, __shfl_xor(m, 1));
            float e[CT]; float ps = 0.0f;
#pragma unroll
            for (int cc = 0; cc < CT; ++cc) { e[cc] = expf(acc[r][cc] - m); ps = ps + e[cc]; }
            float tot = ps + __shfl_xor(ps, 1);
            const float* xr = B + (size_t)o * cols + jb + tx * CT;
            float pw = 0.0f;
#pragma unroll
            for (int cc = 0; cc < CT; ++cc) {
                float a_ = e[cc] / tot;
                float t = xr[cc] * a_;
                pw = pw + t;
            }
            pw = pw + __shfl_xor(pw, 1);
            if ((tx & 1) == 0)
                pooled[(size_t)o * pstride + (jb >> 4) + (tx >> 1)] = pw;
        }
    }
}

// ---------- kernel 6: nearest-neighbor index ----------
template <int TS>
__global__ void k_nn(const float* __restrict__ tgt, const float* __restrict__ src,
                     int* __restrict__ nn, int Mt, int Ms) {
    __shared__ float sx[TS], sy[TS], sz[TS], sn[TS];
    int b = blockIdx.y;
    int q = blockIdx.x * blockDim.x + threadIdx.x;
    const float* T = tgt + (size_t)b * Mt * 3;
    const float* S = src + (size_t)b * Ms * 3;
    bool act = q < Mt;
    float qx = 0, qy = 0, qz = 0, qn = 0;
    if (act) {
        qx = T[q * 3]; qy = T[q * 3 + 1]; qz = T[q * 3 + 2];
        qn = sumsq3(qx, qy, qz);
    }
    float bd = INFINITY; int bi = 0;
    for (int t0 = 0; t0 < Ms; t0 += TS) {
        __syncthreads();
        for (int j = threadIdx.x; j < TS; j += blockDim.x) {
            int i = t0 + j;
            float px = S[i * 3], py = S[i * 3 + 1], pz = S[i * 3 + 2];
            sx[j] = px; sy[j] = py; sz[j] = pz; sn[j] = sumsq3(px, py, pz);
        }
        __syncthreads();
        if (act) {
            for (int j = 0; j < TS; ++j) {
                float d = (qn + sn[j]) - 2.0f * dot3fma(qx, qy, qz, sx[j], sy[j], sz[j]);
                if (d < bd) { bd = d; bi = t0 + j; }
            }
        }
    }
    if (act) nn[(size_t)b * Mt + q] = bi;
}

// ---------- kernel 7: up-sample + concat + dense + bn_act ----------
template <int CSRC, int CSKIP, int COUT>
__global__ void k_up(const float* __restrict__ srcf, const float* __restrict__ skipf,
                     const int* __restrict__ nn,
                     const float* __restrict__ W, const float* __restrict__ g, const float* __restrict__ bb,
                     float* __restrict__ outf, int Mt, int Ms) {
    __shared__ float fin[CSRC + CSKIP];
    int b = blockIdx.y, n = blockIdx.x, tid = threadIdx.x;
    int j = nn[(size_t)b * Mt + n];
    const float* fs = srcf + ((size_t)b * Ms + j) * CSRC;
    const float* fk = skipf + ((size_t)b * Mt + n) * CSKIP;
    for (int c = tid; c < CSRC; c += blockDim.x) fin[c] = fs[c];
    for (int c = tid; c < CSKIP; c += blockDim.x) fin[CSRC + c] = fk[c];
    __syncthreads();
    for (int o = tid; o < COUT; o += blockDim.x) {
        const float* wr = W + (size_t)o * (CSRC + CSKIP);
        float s = 0.0f;
        for (int c = 0; c < CSRC + CSKIP; ++c) s = __builtin_fmaf(wr[c], fin[c], s);
        float v = s * g[o]; v = v + bb[o];
        outf[((size_t)b * Mt + n) * COUT + o] = lrelu(v);
    }
}

// ---------- kernel 8: final up-sample + Wu1 + head fused ----------
__global__ void k_u1head(const float* __restrict__ srcf, const float* __restrict__ skipf,
                         const int* __restrict__ nn,
                         const float* __restrict__ Wu1, const float* __restrict__ gu1, const float* __restrict__ bu1,
                         const float* __restrict__ Wh1, const float* __restrict__ bh1,
                         const float* __restrict__ Wh2, const float* __restrict__ bh2,
                         float* __restrict__ out, int Mt, int Ms) {
    __shared__ float fin[192];
    __shared__ float d1[64];
    __shared__ float h[64];
    int b = blockIdx.y, n = blockIdx.x, tid = threadIdx.x;
    int j = nn[(size_t)b * Mt + n];
    const float* fs = srcf + ((size_t)b * Ms + j) * 128;
    const float* fk = skipf + ((size_t)b * Mt + n) * 64;
    for (int c = tid; c < 128; c += 64) fin[c] = fs[c];
    fin[128 + tid] = fk[tid];
    __syncthreads();
    {
        const float* wr = Wu1 + (size_t)tid * 192;
        float s = 0.0f;
        for (int c = 0; c < 192; ++c) s = __builtin_fmaf(wr[c], fin[c], s);
        float v = s * gu1[tid]; v = v + bu1[tid];
        d1[tid] = lrelu(v);
    }
    __syncthreads();
    {
        const float* wr = Wh1 + (size_t)tid * 64;
        float s = 0.0f;
        for (int c = 0; c < 64; ++c) s = __builtin_fmaf(wr[c], d1[c], s);
        float v = s + bh1[tid];
        h[tid] = lrelu(v);
    }
    __syncthreads();
    if (tid < 13) {
        const float* wr = Wh2 + (size_t)tid * 64;
        float s = 0.0f;
        for (int c = 0; c < 64; ++c) s = __builtin_fmaf(wr[c], h[c], s);
        out[((size_t)b * Mt + n) * 13 + tid] = s + bh2[tid];
    }
}

// ---------- launch ----------
extern "C" void kernel_launch(void* const* d_in, const int* in_sizes, int n_in,
                              void* d_out, int out_size, void* d_ws, size_t ws_size,
                              hipStream_t stream) {
    const float* xyz  = (const float*)d_in[0];
    const float* feat = (const float*)d_in[1];
    const int*   sel1 = (const int*)d_in[2];
    const int*   sel2 = (const int*)d_in[3];
    const float* Wpre = (const float*)d_in[4];
    const float* gpre = (const float*)d_in[5];
    const float* bpre = (const float*)d_in[6];
    const float* W1m  = (const float*)d_in[7];
    const float* g1m  = (const float*)d_in[8];
    const float* b1m  = (const float*)d_in[9];
    const float* W1s  = (const float*)d_in[10];
    const float* W1p  = (const float*)d_in[11];
    const float* g1p  = (const float*)d_in[12];
    const float* b1p  = (const float*)d_in[13];
    const float* W2m  = (const float*)d_in[14];
    const float* g2m  = (const float*)d_in[15];
    const float* b2m  = (const float*)d_in[16];
    const float* W2s  = (const float*)d_in[17];
    const float* W2p  = (const float*)d_in[18];
    const float* g2p  = (const float*)d_in[19];
    const float* b2p  = (const float*)d_in[20];
    const float* W3m  = (const float*)d_in[21];
    const float* g3m  = (const float*)d_in[22];
    const float* b3m  = (const float*)d_in[23];
    const float* W3s  = (const float*)d_in[24];
    const float* W3p  = (const float*)d_in[25];
    const float* g3p  = (const float*)d_in[26];
    const float* b3p  = (const float*)d_in[27];
    const float* Wu2  = (const float*)d_in[28];
    const float* gu2  = (const float*)d_in[29];
    const float* bu2  = (const float*)d_in[30];
    const float* Wu1  = (const float*)d_in[31];
    const float* gu1  = (const float*)d_in[32];
    const float* bu1  = (const float*)d_in[33];
    const float* Wh1  = (const float*)d_in[34];
    const float* bh1  = (const float*)d_in[35];
    const float* Wh2  = (const float*)d_in[36];
    const float* bh2  = (const float*)d_in[37];
    float* out = (float*)d_out;

    char* w = (char*)d_ws;
    auto alloc = [&](size_t n) { char* p = w; w += (n + 255) & ~(size_t)255; return p; };
    float* x0   = (float*)alloc((size_t)2 * 8192 * 64 * 4);
    float* x1   = (float*)alloc((size_t)2 * 8192 * 64 * 4);
    float* f1   = (float*)alloc((size_t)2 * 4096 * 64 * 4);
    float* x2   = (float*)alloc((size_t)2 * 4096 * 128 * 4);
    float* f2   = (float*)alloc((size_t)2 * 2048 * 128 * 4);
    float* x3   = (float*)alloc((size_t)2 * 2048 * 256 * 4);
    float* d2f  = (float*)alloc((size_t)2 * 4096 * 128 * 4);
    float* xyz1 = (float*)alloc((size_t)2 * 4096 * 3 * 4);
    float* xyz2 = (float*)alloc((size_t)2 * 2048 * 3 * 4);
    int* n0   = (int*)alloc((size_t)2 * 8192 * 16 * 4);
    int* n1   = (int*)alloc((size_t)2 * 4096 * 16 * 4);
    int* n2   = (int*)alloc((size_t)2 * 2048 * 16 * 4);
    int* nnu2 = (int*)alloc((size_t)2 * 4096 * 4);
    int* nnu1 = (int*)alloc((size_t)2 * 8192 * 4);
    // chunked LFA scratch (reused across levels)
    float* XIN  = (float*)alloc((size_t)74 * 65536 * 4);   // max CR x chunk
    float* XMID = (float*)alloc((size_t)64 * 65536 * 4);   // == 128*32768 == 256*16384
    float* pooled = (float*)alloc((size_t)64 * 16384 * 4); // == 128*8192 == 256*4096

    k_pre<<<128, 128, 0, stream>>>(feat, Wpre, gpre, bpre, x0);

    // ---- level 1 ----
    k_knn<256><<<dim3(128, 2), 64, 0, stream>>>(xyz, n0, 8192);
    {
        const int cols = 2 * 8192 * 16, chunk = cols / 4;
        for (int s = 0; s < 4; ++s) {
            int j0 = s * chunk;
            k_encode<64><<<chunk / 256, 256, 0, stream>>>(xyz, x0, n0, XIN, 8192, chunk, j0);
            k_gemm<64, 128, 16, 1><<<dim3(chunk / 128, 1), 256, 0, stream>>>(
                W1m, XIN, g1m, b1m, XMID, nullptr, 64, 74, chunk, 0);
            k_gemm<64, 128, 16, 3><<<dim3(chunk / 128, 1), 256, 0, stream>>>(
                W1s, XMID, nullptr, nullptr, nullptr, pooled + j0 / 16, 64, 64, chunk, cols / 16);
        }
        k_gemm<64, 128, 16, 2><<<dim3(16384 / 128, 1), 256, 0, stream>>>(
            W1p, pooled, g1p, b1p, x1, nullptr, 64, 64, 16384, 0);
    }

    // ---- level 2 ----
    k_gather<64><<<dim3(4096, 2), 64, 0, stream>>>(xyz, x1, sel1, xyz1, f1, 4096, 8192);
    k_knn<256><<<dim3(64, 2), 64, 0, stream>>>(xyz1, n1, 4096);
    {
        const int cols = 2 * 4096 * 16, chunk = cols / 4;
        for (int s = 0; s < 4; ++s) {
            int j0 = s * chunk;
            k_encode<64><<<chunk / 256, 256, 0, stream>>>(xyz1, f1, n1, XIN, 4096, chunk, j0);
            k_gemm<128, 128, 16, 1><<<dim3(chunk / 128, 1), 256, 0, stream>>>(
                W2m, XIN, g2m, b2m, XMID, nullptr, 128, 74, chunk, 0);
            k_gemm<128, 128, 16, 3><<<dim3(chunk / 128, 1), 256, 0, stream>>>(
                W2s, XMID, nullptr, nullptr, nullptr, pooled + j0 / 16, 128, 128, chunk, cols / 16);
        }
        k_gemm<128, 128, 16, 2><<<dim3(8192 / 128, 1), 256, 0, stream>>>(
            W2p, pooled, g2p, b2p, x2, nullptr, 128, 128, 8192, 0);
    }

    // ---- level 3 ----
    k_gather<128><<<dim3(2048, 2), 64, 0, stream>>>(xyz1, x2, sel2, xyz2, f2, 2048, 4096);
    k_knn<256><<<dim3(32, 2), 64, 0, stream>>>(xyz2, n2, 2048);
    {
        const int cols = 2 * 2048 * 16, chunk = cols / 4;
        for (int s = 0; s < 4; ++s) {
            int j0 = s * chunk;
            k_encode<128><<<chunk / 256, 256, 0, stream>>>(xyz2, f2, n2, XIN, 2048, chunk, j0);
            k_gemm<128, 128, 16, 1><<<dim3(chunk / 128, 2), 256, 0, stream>>>(
                W3m, XIN, g3m, b3m, XMID, nullptr, 256, 138, chunk, 0);
            k_gemm<128, 128, 16, 3><<<dim3(chunk / 128, 2), 256, 0, stream>>>(
                W3s, XMID, nullptr, nullptr, nullptr, pooled + j0 / 16, 256, 256, chunk, cols / 16);
        }
        k_gemm<128, 128, 16, 2><<<dim3(4096 / 128, 2), 256, 0, stream>>>(
            W3p, pooled, g3p, b3p, x3, nullptr, 256, 256, 4096, 0);
    }

    // ---- decoder ----
    k_nn<256><<<dim3(64, 2), 64, 0, stream>>>(xyz1, xyz2, nnu2, 4096, 2048);
    k_up<256, 128, 128><<<dim3(4096, 2), 128, 0, stream>>>(x3, x2, nnu2, Wu2, gu2, bu2,
                                                           d2f, 4096, 2048);
    k_nn<256><<<dim3(128, 2), 64, 0, stream>>>(xyz, xyz1, nnu1, 8192, 4096);
    k_u1head<<<dim3(8192, 2), 64, 0, stream>>>(d2f, x1, nnu1, Wu1, gu1, bu1, Wh1, bh1,
                                               Wh2, bh2, out, 8192, 4096);
}

// Round 3
// 2856.421 us; speedup vs baseline: 2.0153x; 1.4752x over previous
//
#include <hip/hip_runtime.h>
#include <hip/hip_bf16.h>

#pragma clang fp contract(off)

// ---------- numeric helpers (rounding-faithful to reference) ----------
__device__ __forceinline__ float lrelu(float v) { return v >= 0.0f ? v : 0.1f * v; }

__device__ __forceinline__ float sumsq3(float x, float y, float z) {
    return ((x * x) + (y * y)) + (z * z);
}

__device__ __forceinline__ float dot3fma(float ax, float ay, float az,
                                         float bx, float by, float bz) {
    float d = ax * bx;
    d = __builtin_fmaf(ay, by, d);
    d = __builtin_fmaf(az, bz, d);
    return d;
}

// ---------- kernel 1: pre-MLP ----------
__global__ void k_pre(const float* __restrict__ feat, const float* __restrict__ W,
                      const float* __restrict__ g, const float* __restrict__ bb,
                      float* __restrict__ x0) {
    int p = blockIdx.x * blockDim.x + threadIdx.x;
    if (p >= 2 * 8192) return;
    const float* f = feat + (size_t)p * 6;
    float fv[6];
#pragma unroll
    for (int c = 0; c < 6; ++c) fv[c] = f[c];
    float* out = x0 + (size_t)p * 64;
    for (int o = 0; o < 64; ++o) {
        float s = 0.0f;
#pragma unroll
        for (int c = 0; c < 6; ++c) s = __builtin_fmaf(W[o * 6 + c], fv[c], s);
        float v = s * g[o];
        v = v + bb[o];
        out[o] = lrelu(v);
    }
}

// ---------- kernel 2: candidate-parallel KNN (top-16 by (d2, idx)) ----------
// LPQ lanes per query; each lane scans a strided 1/LPQ of candidates keeping a
// sorted top-16 (ascending (d,idx)); merge LPQ lists lexicographically.
template <int LPQ, int TS>
__launch_bounds__(256)
__global__ void k_knn_par(const float* __restrict__ xyz, int* __restrict__ out_idx, int Npts) {
    constexpr int QPB = 256 / LPQ;
    __shared__ float sx[TS], sy[TS], sz[TS], sn[TS];
    __shared__ float md[QPB][LPQ][17];
    __shared__ int   mi[QPB][LPQ][17];
    int b = blockIdx.y;
    int tid = threadIdx.x;
    int qi = tid / LPQ;
    int l = tid % LPQ;
    int q = blockIdx.x * QPB + qi;
    const float* X = xyz + (size_t)b * Npts * 3;
    float qx = X[q * 3], qy = X[q * 3 + 1], qz = X[q * 3 + 2];
    float qn = sumsq3(qx, qy, qz);

    float dist[16]; int idx[16];
#pragma unroll
    for (int u = 0; u < 16; ++u) { dist[u] = INFINITY; idx[u] = 0x7fffffff; }

    auto ins = [&](float cd, int ci) {
#pragma unroll
        for (int u = 0; u < 16; ++u) {   // strict <: equal-d later index stays after
            bool sw = cd < dist[u];
            float td = sw ? dist[u] : cd; int ti = sw ? idx[u] : ci;
            dist[u] = sw ? cd : dist[u];  idx[u] = sw ? ci : idx[u];
            cd = td; ci = ti;
        }
    };

    for (int t0 = 0; t0 < Npts; t0 += TS) {
        __syncthreads();
        for (int j = tid; j < TS; j += 256) {
            int i = t0 + j;
            float px = X[i * 3], py = X[i * 3 + 1], pz = X[i * 3 + 2];
            sx[j] = px; sy[j] = py; sz[j] = pz; sn[j] = sumsq3(px, py, pz);
        }
        __syncthreads();
        for (int j = l; j < TS; j += 4 * LPQ) {
            int j1 = j + LPQ, j2 = j + 2 * LPQ, j3 = j + 3 * LPQ;
            float d0 = (qn + sn[j])  - 2.0f * dot3fma(qx, qy, qz, sx[j],  sy[j],  sz[j]);
            float d1 = (qn + sn[j1]) - 2.0f * dot3fma(qx, qy, qz, sx[j1], sy[j1], sz[j1]);
            float d2 = (qn + sn[j2]) - 2.0f * dot3fma(qx, qy, qz, sx[j2], sy[j2], sz[j2]);
            float d3 = (qn + sn[j3]) - 2.0f * dot3fma(qx, qy, qz, sx[j3], sy[j3], sz[j3]);
            float mm = fminf(fminf(d0, d1), fminf(d2, d3));
            if (mm < dist[15]) {
                if (d0 < dist[15]) ins(d0, t0 + j);
                if (d1 < dist[15]) ins(d1, t0 + j1);
                if (d2 < dist[15]) ins(d2, t0 + j2);
                if (d3 < dist[15]) ins(d3, t0 + j3);
            }
        }
    }

    __syncthreads();
#pragma unroll
    for (int u = 0; u < 16; ++u) { md[qi][l][u] = dist[u]; mi[qi][l][u] = idx[u]; }
    md[qi][l][16] = INFINITY; mi[qi][l][16] = 0x7fffffff;
    __syncthreads();

    if (l == 0) {
        unsigned long long hp0 = 0, hp1 = 0;   // 5-bit packed heads (no scratch array)
        int* o = out_idx + ((size_t)b * Npts + q) * 16;
        for (int r = 0; r < 16; ++r) {
            float bd = INFINITY; int bi = 0x7fffffff; int bl = 0;
#pragma unroll
            for (int i = 0; i < LPQ; ++i) {
                int h = (int)(((i < 8 ? hp0 : hp1) >> ((i & 7) * 5)) & 31);
                float dv = md[qi][i][h];
                int iv = mi[qi][i][h];
                bool better = (dv < bd) || ((dv == bd) && (iv < bi));
                bd = better ? dv : bd;
                bi = better ? iv : bi;
                bl = better ? i : bl;
            }
            unsigned long long inc = 1ull << ((bl & 7) * 5);
            hp0 += (bl < 8) ? inc : 0ull;
            hp1 += (bl < 8) ? 0ull : inc;
            o[r] = bi;
        }
    }
}

// ---------- kernel 3: gather selected points ----------
template <int C>
__global__ void k_gather(const float* __restrict__ src_xyz, const float* __restrict__ src_feat,
                         const int* __restrict__ sel, float* __restrict__ dst_xyz,
                         float* __restrict__ dst_feat, int M, int Nsrc) {
    int b = blockIdx.y, m = blockIdx.x;
    int s = sel[(size_t)b * M + m];
    const float* fx = src_xyz + ((size_t)b * Nsrc + s) * 3;
    const float* ff = src_feat + ((size_t)b * Nsrc + s) * C;
    float* dx = dst_xyz + ((size_t)b * M + m) * 3;
    float* df = dst_feat + ((size_t)b * M + m) * C;
    if (threadIdx.x < 3) dx[threadIdx.x] = fx[threadIdx.x];
    for (int c = threadIdx.x; c < C; c += blockDim.x) df[c] = ff[c];
}

// ---------- kernel 4: encode — build XIN[CR][colsC] for a column chunk ----------
template <int CIN>
__global__ void k_encode(const float* __restrict__ xyz, const float* __restrict__ feat,
                         const int* __restrict__ kn, float* __restrict__ XIN,
                         int Npts, int colsC, int j0) {
    int jl = blockIdx.x * 256 + threadIdx.x;
    if (jl >= colsC) return;
    int jg = j0 + jl;
    int p = jg >> 4;
    int b = p / Npts, n = p - b * Npts;
    int nbr = kn[jg];
    const float* X = xyz + (size_t)b * Npts * 3;
    float cx = X[n * 3 + 0], cy = X[n * 3 + 1], cz = X[n * 3 + 2];
    float nx = X[nbr * 3 + 0], ny = X[nbr * 3 + 1], nz = X[nbr * 3 + 2];
    const float* fr = feat + ((size_t)b * Npts + nbr) * CIN;
    for (int c = 0; c < CIN; ++c) XIN[(size_t)c * colsC + jl] = fr[c];
    float dx = cx - nx, dy = cy - ny, dz = cz - nz;
    float dn = sqrtf(sumsq3(dx, dy, dz));
    float* Xr = XIN + (size_t)CIN * colsC + jl;
    size_t st = (size_t)colsC;
    Xr[0 * st] = dx; Xr[1 * st] = dy; Xr[2 * st] = dz; Xr[3 * st] = dn;
    Xr[4 * st] = cx; Xr[5 * st] = cy; Xr[6 * st] = cz;
    Xr[7 * st] = nx; Xr[8 * st] = ny; Xr[9 * st] = nz;
}

// ---------- kernel 5: register-tiled f32 GEMM with fused epilogues ----------
template <int BM, int BN, int BK, int EPI>
__launch_bounds__(256)
__global__ void k_gemm(const float* __restrict__ A, const float* __restrict__ B,
                       const float* __restrict__ g, const float* __restrict__ bb,
                       float* __restrict__ C, float* __restrict__ pooled,
                       int M, int K, int cols, int pstride) {
    static_assert(BN == 128 && BK == 16, "layout assumptions");
    constexpr int RT = BM / 16, CT = BN / 16;
    __shared__ float sA[BK][BM + 4];
    __shared__ float sB[BK][BN];
    int tid = threadIdx.x;
    int tx = tid & 15, ty = tid >> 4;
    int jb = blockIdx.x * BN;
    int om = blockIdx.y * BM;

    float acc[RT][CT];
#pragma unroll
    for (int r = 0; r < RT; ++r)
#pragma unroll
        for (int c = 0; c < CT; ++c) acc[r][c] = 0.0f;

    for (int ck = 0; ck < K; ck += BK) {
        {
            int c = tid & 15;
            int r0 = tid >> 4;
            int cc = ck + c;
            for (int rr = r0; rr < BM; rr += 16) {
                float v = 0.0f;
                if (cc < K) v = A[(size_t)(om + rr) * K + cc];
                sA[c][rr] = v;
            }
        }
        {
            int jj = tid & 127;
            int c0 = tid >> 7;
            for (int cp = c0; cp < BK; cp += 2) {
                float v = 0.0f;
                if (ck + cp < K) v = B[(size_t)(ck + cp) * cols + jb + jj];
                sB[cp][jj] = v;
            }
        }
        __syncthreads();
#pragma unroll
        for (int c = 0; c < BK; ++c) {
            float a[RT], bv[CT];
            *reinterpret_cast<float4*>(&a[0]) =
                *reinterpret_cast<const float4*>(&sA[c][ty * RT]);
            if (RT == 8)
                *reinterpret_cast<float4*>(&a[4]) =
                    *reinterpret_cast<const float4*>(&sA[c][ty * RT + 4]);
            *reinterpret_cast<float4*>(&bv[0]) =
                *reinterpret_cast<const float4*>(&sB[c][tx * CT]);
            *reinterpret_cast<float4*>(&bv[4]) =
                *reinterpret_cast<const float4*>(&sB[c][tx * CT + 4]);
#pragma unroll
            for (int r = 0; r < RT; ++r)
#pragma unroll
                for (int cc = 0; cc < CT; ++cc)
                    acc[r][cc] = __builtin_fmaf(a[r], bv[cc], acc[r][cc]);
        }
        __syncthreads();
    }

    if (EPI == 1) {
#pragma unroll
        for (int r = 0; r < RT; ++r) {
            int o = om + ty * RT + r;
            float gg = g[o], bbv = bb[o];
#pragma unroll
            for (int cc = 0; cc < CT; ++cc) {
                float v = acc[r][cc] * gg;
                v = v + bbv;
                C[(size_t)o * cols + jb + tx * CT + cc] = lrelu(v);
            }
        }
    } else if (EPI == 2) {
#pragma unroll
        for (int r = 0; r < RT; ++r) {
            int o = om + ty * RT + r;
            float gg = g[o], bbv = bb[o];
#pragma unroll
            for (int cc = 0; cc < CT; ++cc) {
                float v = acc[r][cc] * gg;
                v = v + bbv;
                C[(size_t)(jb + tx * CT + cc) * M + o] = lrelu(v);
            }
        }
    } else if (EPI == 3) {
#pragma unroll
        for (int r = 0; r < RT; ++r) {
            int o = om + ty * RT + r;
            float m = acc[r][0];
#pragma unroll
            for (int cc = 1; cc < CT; ++cc) m = fmaxf(m, acc[r][cc]);
            m = fmaxf(m, __shfl_xor(m, 1));
            float e[CT]; float ps = 0.0f;
#pragma unroll
            for (int cc = 0; cc < CT; ++cc) { e[cc] = expf(acc[r][cc] - m); ps = ps + e[cc]; }
            float tot = ps + __shfl_xor(ps, 1);
            const float* xr = B + (size_t)o * cols + jb + tx * CT;
            float pw = 0.0f;
#pragma unroll
            for (int cc = 0; cc < CT; ++cc) {
                float a_ = e[cc] / tot;
                float t = xr[cc] * a_;
                pw = pw + t;
            }
            pw = pw + __shfl_xor(pw, 1);
            if ((tx & 1) == 0)
                pooled[(size_t)o * pstride + (jb >> 4) + (tx >> 1)] = pw;
        }
    }
}

// ---------- kernel 6: candidate-parallel nearest-neighbor argmin ----------
template <int LPQ, int TS>
__launch_bounds__(256)
__global__ void k_nn_par(const float* __restrict__ tgt, const float* __restrict__ src,
                         int* __restrict__ nn, int Mt, int Ms) {
    constexpr int QPB = 256 / LPQ;
    __shared__ float sx[TS], sy[TS], sz[TS], sn[TS];
    int b = blockIdx.y;
    int tid = threadIdx.x;
    int qi = tid / LPQ;
    int l = tid % LPQ;
    int q = blockIdx.x * QPB + qi;
    const float* T = tgt + (size_t)b * Mt * 3;
    const float* S = src + (size_t)b * Ms * 3;
    float qx = T[q * 3], qy = T[q * 3 + 1], qz = T[q * 3 + 2];
    float qn = sumsq3(qx, qy, qz);
    float bd = INFINITY; int bi = 0x7fffffff;
    for (int t0 = 0; t0 < Ms; t0 += TS) {
        __syncthreads();
        for (int j = tid; j < TS; j += 256) {
            int i = t0 + j;
            float px = S[i * 3], py = S[i * 3 + 1], pz = S[i * 3 + 2];
            sx[j] = px; sy[j] = py; sz[j] = pz; sn[j] = sumsq3(px, py, pz);
        }
        __syncthreads();
        for (int j = l; j < TS; j += LPQ) {
            float d = (qn + sn[j]) - 2.0f * dot3fma(qx, qy, qz, sx[j], sy[j], sz[j]);
            if (d < bd) { bd = d; bi = t0 + j; }   // ascending idx per lane
        }
    }
#pragma unroll
    for (int s = LPQ / 2; s; s >>= 1) {
        float od = __shfl_xor(bd, s);
        int oi = __shfl_xor(bi, s);
        bool better = (od < bd) || ((od == bd) && (oi < bi));
        bd = better ? od : bd;
        bi = better ? oi : bi;
    }
    if (l == 0) nn[(size_t)b * Mt + q] = bi;
}

// ---------- kernel 7: up-sample + concat + dense + bn_act ----------
template <int CSRC, int CSKIP, int COUT>
__global__ void k_up(const float* __restrict__ srcf, const float* __restrict__ skipf,
                     const int* __restrict__ nn,
                     const float* __restrict__ W, const float* __restrict__ g, const float* __restrict__ bb,
                     float* __restrict__ outf, int Mt, int Ms) {
    __shared__ float fin[CSRC + CSKIP];
    int b = blockIdx.y, n = blockIdx.x, tid = threadIdx.x;
    int j = nn[(size_t)b * Mt + n];
    const float* fs = srcf + ((size_t)b * Ms + j) * CSRC;
    const float* fk = skipf + ((size_t)b * Mt + n) * CSKIP;
    for (int c = tid; c < CSRC; c += blockDim.x) fin[c] = fs[c];
    for (int c = tid; c < CSKIP; c += blockDim.x) fin[CSRC + c] = fk[c];
    __syncthreads();
    for (int o = tid; o < COUT; o += blockDim.x) {
        const float* wr = W + (size_t)o * (CSRC + CSKIP);
        float s = 0.0f;
        for (int c = 0; c < CSRC + CSKIP; ++c) s = __builtin_fmaf(wr[c], fin[c], s);
        float v = s * g[o]; v = v + bb[o];
        outf[((size_t)b * Mt + n) * COUT + o] = lrelu(v);
    }
}

// ---------- kernel 8: final up-sample + Wu1 + head fused ----------
__global__ void k_u1head(const float* __restrict__ srcf, const float* __restrict__ skipf,
                         const int* __restrict__ nn,
                         const float* __restrict__ Wu1, const float* __restrict__ gu1, const float* __restrict__ bu1,
                         const float* __restrict__ Wh1, const float* __restrict__ bh1,
                         const float* __restrict__ Wh2, const float* __restrict__ bh2,
                         float* __restrict__ out, int Mt, int Ms) {
    __shared__ float fin[192];
    __shared__ float d1[64];
    __shared__ float h[64];
    int b = blockIdx.y, n = blockIdx.x, tid = threadIdx.x;
    int j = nn[(size_t)b * Mt + n];
    const float* fs = srcf + ((size_t)b * Ms + j) * 128;
    const float* fk = skipf + ((size_t)b * Mt + n) * 64;
    for (int c = tid; c < 128; c += 64) fin[c] = fs[c];
    fin[128 + tid] = fk[tid];
    __syncthreads();
    {
        const float* wr = Wu1 + (size_t)tid * 192;
        float s = 0.0f;
        for (int c = 0; c < 192; ++c) s = __builtin_fmaf(wr[c], fin[c], s);
        float v = s * gu1[tid]; v = v + bu1[tid];
        d1[tid] = lrelu(v);
    }
    __syncthreads();
    {
        const float* wr = Wh1 + (size_t)tid * 64;
        float s = 0.0f;
        for (int c = 0; c < 64; ++c) s = __builtin_fmaf(wr[c], d1[c], s);
        float v = s + bh1[tid];
        h[tid] = lrelu(v);
    }
    __syncthreads();
    if (tid < 13) {
        const float* wr = Wh2 + (size_t)tid * 64;
        float s = 0.0f;
        for (int c = 0; c < 64; ++c) s = __builtin_fmaf(wr[c], h[c], s);
        out[((size_t)b * Mt + n) * 13 + tid] = s + bh2[tid];
    }
}

// ---------- launch ----------
extern "C" void kernel_launch(void* const* d_in, const int* in_sizes, int n_in,
                              void* d_out, int out_size, void* d_ws, size_t ws_size,
                              hipStream_t stream) {
    const float* xyz  = (const float*)d_in[0];
    const float* feat = (const float*)d_in[1];
    const int*   sel1 = (const int*)d_in[2];
    const int*   sel2 = (const int*)d_in[3];
    const float* Wpre = (const float*)d_in[4];
    const float* gpre = (const float*)d_in[5];
    const float* bpre = (const float*)d_in[6];
    const float* W1m  = (const float*)d_in[7];
    const float* g1m  = (const float*)d_in[8];
    const float* b1m  = (const float*)d_in[9];
    const float* W1s  = (const float*)d_in[10];
    const float* W1p  = (const float*)d_in[11];
    const float* g1p  = (const float*)d_in[12];
    const float* b1p  = (const float*)d_in[13];
    const float* W2m  = (const float*)d_in[14];
    const float* g2m  = (const float*)d_in[15];
    const float* b2m  = (const float*)d_in[16];
    const float* W2s  = (const float*)d_in[17];
    const float* W2p  = (const float*)d_in[18];
    const float* g2p  = (const float*)d_in[19];
    const float* b2p  = (const float*)d_in[20];
    const float* W3m  = (const float*)d_in[21];
    const float* g3m  = (const float*)d_in[22];
    const float* b3m  = (const float*)d_in[23];
    const float* W3s  = (const float*)d_in[24];
    const float* W3p  = (const float*)d_in[25];
    const float* g3p  = (const float*)d_in[26];
    const float* b3p  = (const float*)d_in[27];
    const float* Wu2  = (const float*)d_in[28];
    const float* gu2  = (const float*)d_in[29];
    const float* bu2  = (const float*)d_in[30];
    const float* Wu1  = (const float*)d_in[31];
    const float* gu1  = (const float*)d_in[32];
    const float* bu1  = (const float*)d_in[33];
    const float* Wh1  = (const float*)d_in[34];
    const float* bh1  = (const float*)d_in[35];
    const float* Wh2  = (const float*)d_in[36];
    const float* bh2  = (const float*)d_in[37];
    float* out = (float*)d_out;

    char* w = (char*)d_ws;
    auto alloc = [&](size_t n) { char* p = w; w += (n + 255) & ~(size_t)255; return p; };
    float* x0   = (float*)alloc((size_t)2 * 8192 * 64 * 4);
    float* x1   = (float*)alloc((size_t)2 * 8192 * 64 * 4);
    float* f1   = (float*)alloc((size_t)2 * 4096 * 64 * 4);
    float* x2   = (float*)alloc((size_t)2 * 4096 * 128 * 4);
    float* f2   = (float*)alloc((size_t)2 * 2048 * 128 * 4);
    float* x3   = (float*)alloc((size_t)2 * 2048 * 256 * 4);
    float* d2f  = (float*)alloc((size_t)2 * 4096 * 128 * 4);
    float* xyz1 = (float*)alloc((size_t)2 * 4096 * 3 * 4);
    float* xyz2 = (float*)alloc((size_t)2 * 2048 * 3 * 4);
    int* n0   = (int*)alloc((size_t)2 * 8192 * 16 * 4);
    int* n1   = (int*)alloc((size_t)2 * 4096 * 16 * 4);
    int* n2   = (int*)alloc((size_t)2 * 2048 * 16 * 4);
    int* nnu2 = (int*)alloc((size_t)2 * 4096 * 4);
    int* nnu1 = (int*)alloc((size_t)2 * 8192 * 4);
    float* XIN  = (float*)alloc((size_t)74 * 65536 * 4);
    float* XMID = (float*)alloc((size_t)64 * 65536 * 4);
    float* pooled = (float*)alloc((size_t)64 * 16384 * 4);

    k_pre<<<128, 128, 0, stream>>>(feat, Wpre, gpre, bpre, x0);

    // ---- level 1 ----
    k_knn_par<8, 512><<<dim3(256, 2), 256, 0, stream>>>(xyz, n0, 8192);
    {
        const int cols = 2 * 8192 * 16, chunk = cols / 4;
        for (int s = 0; s < 4; ++s) {
            int j0 = s * chunk;
            k_encode<64><<<chunk / 256, 256, 0, stream>>>(xyz, x0, n0, XIN, 8192, chunk, j0);
            k_gemm<64, 128, 16, 1><<<dim3(chunk / 128, 1), 256, 0, stream>>>(
                W1m, XIN, g1m, b1m, XMID, nullptr, 64, 74, chunk, 0);
            k_gemm<64, 128, 16, 3><<<dim3(chunk / 128, 1), 256, 0, stream>>>(
                W1s, XMID, nullptr, nullptr, nullptr, pooled + j0 / 16, 64, 64, chunk, cols / 16);
        }
        k_gemm<64, 128, 16, 2><<<dim3(16384 / 128, 1), 256, 0, stream>>>(
            W1p, pooled, g1p, b1p, x1, nullptr, 64, 64, 16384, 0);
    }

    // ---- level 2 ----
    k_gather<64><<<dim3(4096, 2), 64, 0, stream>>>(xyz, x1, sel1, xyz1, f1, 4096, 8192);
    k_knn_par<8, 512><<<dim3(128, 2), 256, 0, stream>>>(xyz1, n1, 4096);
    {
        const int cols = 2 * 4096 * 16, chunk = cols / 4;
        for (int s = 0; s < 4; ++s) {
            int j0 = s * chunk;
            k_encode<64><<<chunk / 256, 256, 0, stream>>>(xyz1, f1, n1, XIN, 4096, chunk, j0);
            k_gemm<128, 128, 16, 1><<<dim3(chunk / 128, 1), 256, 0, stream>>>(
                W2m, XIN, g2m, b2m, XMID, nullptr, 128, 74, chunk, 0);
            k_gemm<128, 128, 16, 3><<<dim3(chunk / 128, 1), 256, 0, stream>>>(
                W2s, XMID, nullptr, nullptr, nullptr, pooled + j0 / 16, 128, 128, chunk, cols / 16);
        }
        k_gemm<128, 128, 16, 2><<<dim3(8192 / 128, 1), 256, 0, stream>>>(
            W2p, pooled, g2p, b2p, x2, nullptr, 128, 128, 8192, 0);
    }

    // ---- level 3 ----
    k_gather<128><<<dim3(2048, 2), 64, 0, stream>>>(xyz1, x2, sel2, xyz2, f2, 2048, 4096);
    k_knn_par<16, 512><<<dim3(128, 2), 256, 0, stream>>>(xyz2, n2, 2048);
    {
        const int cols = 2 * 2048 * 16, chunk = cols / 4;
        for (int s = 0; s < 4; ++s) {
            int j0 = s * chunk;
            k_encode<128><<<chunk / 256, 256, 0, stream>>>(xyz2, f2, n2, XIN, 2048, chunk, j0);
            k_gemm<128, 128, 16, 1><<<dim3(chunk / 128, 2), 256, 0, stream>>>(
                W3m, XIN, g3m, b3m, XMID, nullptr, 256, 138, chunk, 0);
            k_gemm<128, 128, 16, 3><<<dim3(chunk / 128, 2), 256, 0, stream>>>(
                W3s, XMID, nullptr, nullptr, nullptr, pooled + j0 / 16, 256, 256, chunk, cols / 16);
        }
        k_gemm<128, 128, 16, 2><<<dim3(4096 / 128, 2), 256, 0, stream>>>(
            W3p, pooled, g3p, b3p, x3, nullptr, 256, 256, 4096, 0);
    }

    // ---- decoder ----
    k_nn_par<8, 512><<<dim3(128, 2), 256, 0, stream>>>(xyz1, xyz2, nnu2, 4096, 2048);
    k_up<256, 128, 128><<<dim3(4096, 2), 128, 0, stream>>>(x3, x2, nnu2, Wu2, gu2, bu2,
                                                           d2f, 4096, 2048);
    k_nn_par<8, 512><<<dim3(256, 2), 256, 0, stream>>>(xyz, xyz1, nnu1, 8192, 4096);
    k_u1head<<<dim3(8192, 2), 64, 0, stream>>>(d2f, x1, nnu1, Wu1, gu1, bu1, Wh1, bh1,
                                               Wh2, bh2, out, 8192, 4096);
}

// Round 5
// 2299.842 us; speedup vs baseline: 2.5030x; 1.2420x over previous
//
#include <hip/hip_runtime.h>
#include <hip/hip_bf16.h>

#pragma clang fp contract(off)

// ---------- numeric helpers (rounding-faithful to reference) ----------
__device__ __forceinline__ float lrelu(float v) { return v >= 0.0f ? v : 0.1f * v; }

__device__ __forceinline__ float sumsq3(float x, float y, float z) {
    return ((x * x) + (y * y)) + (z * z);
}

__device__ __forceinline__ float dot3fma(float ax, float ay, float az,
                                         float bx, float by, float bz) {
    float d = ax * bx;
    d = __builtin_fmaf(ay, by, d);
    d = __builtin_fmaf(az, bz, d);
    return d;
}

// monotone key: integer compare on key == lexicographic (d, idx) compare
__device__ __forceinline__ unsigned long long packkey(float d, int i) {
    unsigned u = __float_as_uint(d);
    u = (u & 0x80000000u) ? ~u : (u | 0x80000000u);
    return ((unsigned long long)u << 32) | (unsigned)i;
}

__device__ __forceinline__ unsigned long long shfl_xor_u64(unsigned long long v, int mask) {
    int lo = __shfl_xor((int)(v & 0xffffffffull), mask);
    int hi = __shfl_xor((int)(v >> 32), mask);
    return ((unsigned long long)(unsigned)hi << 32) | (unsigned)lo;
}

// ---------- kernel 1: pre-MLP ----------
__global__ void k_pre(const float* __restrict__ feat, const float* __restrict__ W,
                      const float* __restrict__ g, const float* __restrict__ bb,
                      float* __restrict__ x0) {
    int p = blockIdx.x * blockDim.x + threadIdx.x;
    if (p >= 2 * 8192) return;
    const float* f = feat + (size_t)p * 6;
    float fv[6];
#pragma unroll
    for (int c = 0; c < 6; ++c) fv[c] = f[c];
    float* out = x0 + (size_t)p * 64;
    for (int o = 0; o < 64; ++o) {
        float s = 0.0f;
#pragma unroll
        for (int c = 0; c < 6; ++c) s = __builtin_fmaf(W[o * 6 + c], fv[c], s);
        float v = s * g[o];
        v = v + bb[o];
        out[o] = lrelu(v);
    }
}

// ---------- kernel 2: register-merge KNN (top-16 by packed (d2, idx) key) ----------
// LPQ lanes/query; per-lane sorted top-16 of packed u64 keys; butterfly shfl
// merge (partner reversed + elementwise min -> bitonic -> 4-stage clean).
template <int LPQ, int TS>
__launch_bounds__(256)
__global__ void k_knn_reg(const float* __restrict__ xyz, int* __restrict__ out_idx, int Npts) {
    constexpr int QPB = 256 / LPQ;
    __shared__ float sx[TS], sy[TS], sz[TS], sn[TS];
    int b = blockIdx.y;
    int tid = threadIdx.x;
    int qi = tid / LPQ;
    int l = tid % LPQ;
    int q = blockIdx.x * QPB + qi;
    const float* X = xyz + (size_t)b * Npts * 3;
    float qx = X[q * 3], qy = X[q * 3 + 1], qz = X[q * 3 + 2];
    float qn = sumsq3(qx, qy, qz);

    unsigned long long key[16];
#pragma unroll
    for (int u = 0; u < 16; ++u) key[u] = ~0ull;

    for (int t0 = 0; t0 < Npts; t0 += TS) {
        __syncthreads();
        for (int j = tid; j < TS; j += 256) {
            int i = t0 + j;
            float px = X[i * 3], py = X[i * 3 + 1], pz = X[i * 3 + 2];
            sx[j] = px; sy[j] = py; sz[j] = pz; sn[j] = sumsq3(px, py, pz);
        }
        __syncthreads();
        for (int j = l; j < TS; j += LPQ) {
            float d = (qn + sn[j]) - 2.0f * dot3fma(qx, qy, qz, sx[j], sy[j], sz[j]);
            unsigned long long ck = packkey(d, t0 + j);
            if (ck < key[15]) {
#pragma unroll
                for (int u = 0; u < 16; ++u) {   // static-index bubble insert
                    bool sw = ck < key[u];
                    unsigned long long t = sw ? key[u] : ck;
                    key[u] = sw ? ck : key[u];
                    ck = t;
                }
            }
        }
    }

    // butterfly merge across the LPQ lanes of this query
    for (int mask = 1; mask < LPQ; mask <<= 1) {
        unsigned long long ok[16];
#pragma unroll
        for (int i = 0; i < 16; ++i) ok[i] = shfl_xor_u64(key[15 - i], mask);
#pragma unroll
        for (int i = 0; i < 16; ++i) key[i] = ok[i] < key[i] ? ok[i] : key[i];
        // key[] is bitonic; 4-stage clean sorts ascending
#pragma unroll
        for (int dstep = 8; dstep >= 1; dstep >>= 1) {
#pragma unroll
            for (int i = 0; i < 16; ++i) {
                if (!(i & dstep)) {
                    int jj = i + dstep;
                    unsigned long long lo = key[jj] < key[i] ? key[jj] : key[i];
                    unsigned long long hi = key[jj] < key[i] ? key[i] : key[jj];
                    key[i] = lo; key[jj] = hi;
                }
            }
        }
    }

    if (l == 0) {
        int* o = out_idx + ((size_t)b * Npts + q) * 16;
#pragma unroll
        for (int u = 0; u < 16; ++u) o[u] = (int)(unsigned)(key[u] & 0xffffffffull);
    }
}

// ---------- kernel 3: gather selected points ----------
template <int C>
__global__ void k_gather(const float* __restrict__ src_xyz, const float* __restrict__ src_feat,
                         const int* __restrict__ sel, float* __restrict__ dst_xyz,
                         float* __restrict__ dst_feat, int M, int Nsrc) {
    int b = blockIdx.y, m = blockIdx.x;
    int s = sel[(size_t)b * M + m];
    const float* fx = src_xyz + ((size_t)b * Nsrc + s) * 3;
    const float* ff = src_feat + ((size_t)b * Nsrc + s) * C;
    float* dx = dst_xyz + ((size_t)b * M + m) * 3;
    float* df = dst_feat + ((size_t)b * M + m) * C;
    if (threadIdx.x < 3) dx[threadIdx.x] = fx[threadIdx.x];
    for (int c = threadIdx.x; c < C; c += blockDim.x) df[c] = ff[c];
}

// ---------- kernel 4: encode — build XIN[CR][colsC] for a column chunk ----------
template <int CIN>
__global__ void k_encode(const float* __restrict__ xyz, const float* __restrict__ feat,
                         const int* __restrict__ kn, float* __restrict__ XIN,
                         int Npts, int colsC, int j0) {
    int jl = blockIdx.x * 256 + threadIdx.x;
    if (jl >= colsC) return;
    int jg = j0 + jl;
    int p = jg >> 4;
    int b = p / Npts, n = p - b * Npts;
    int nbr = kn[jg];
    const float* X = xyz + (size_t)b * Npts * 3;
    float cx = X[n * 3 + 0], cy = X[n * 3 + 1], cz = X[n * 3 + 2];
    float nx = X[nbr * 3 + 0], ny = X[nbr * 3 + 1], nz = X[nbr * 3 + 2];
    const float* fr = feat + ((size_t)b * Npts + nbr) * CIN;
    for (int c = 0; c < CIN; ++c) XIN[(size_t)c * colsC + jl] = fr[c];
    float dx = cx - nx, dy = cy - ny, dz = cz - nz;
    float dn = sqrtf(sumsq3(dx, dy, dz));
    float* Xr = XIN + (size_t)CIN * colsC + jl;
    size_t st = (size_t)colsC;
    Xr[0 * st] = dx; Xr[1 * st] = dy; Xr[2 * st] = dz; Xr[3 * st] = dn;
    Xr[4 * st] = cx; Xr[5 * st] = cy; Xr[6 * st] = cz;
    Xr[7 * st] = nx; Xr[8 * st] = ny; Xr[9 * st] = nz;
}

// ---------- kernel 5: register-tiled f32 GEMM with fused epilogues ----------
template <int BM, int BN, int BK, int EPI>
__launch_bounds__(256)
__global__ void k_gemm(const float* __restrict__ A, const float* __restrict__ B,
                       const float* __restrict__ g, const float* __restrict__ bb,
                       float* __restrict__ C, float* __restrict__ pooled,
                       int M, int K, int cols, int pstride) {
    static_assert(BN == 128 && BK == 16, "layout assumptions");
    constexpr int RT = BM / 16, CT = BN / 16;
    __shared__ float sA[BK][BM + 4];
    __shared__ float sB[BK][BN];
    int tid = threadIdx.x;
    int tx = tid & 15, ty = tid >> 4;
    int jb = blockIdx.x * BN;
    int om = blockIdx.y * BM;

    float acc[RT][CT];
#pragma unroll
    for (int r = 0; r < RT; ++r)
#pragma unroll
        for (int c = 0; c < CT; ++c) acc[r][c] = 0.0f;

    for (int ck = 0; ck < K; ck += BK) {
        {
            int c = tid & 15;
            int r0 = tid >> 4;
            int cc = ck + c;
            for (int rr = r0; rr < BM; rr += 16) {
                float v = 0.0f;
                if (cc < K) v = A[(size_t)(om + rr) * K + cc];
                sA[c][rr] = v;
            }
        }
        {
            int jj = tid & 127;
            int c0 = tid >> 7;
            for (int cp = c0; cp < BK; cp += 2) {
                float v = 0.0f;
                if (ck + cp < K) v = B[(size_t)(ck + cp) * cols + jb + jj];
                sB[cp][jj] = v;
            }
        }
        __syncthreads();
#pragma unroll
        for (int c = 0; c < BK; ++c) {
            float a[RT], bv[CT];
            *reinterpret_cast<float4*>(&a[0]) =
                *reinterpret_cast<const float4*>(&sA[c][ty * RT]);
            if (RT == 8)
                *reinterpret_cast<float4*>(&a[4]) =
                    *reinterpret_cast<const float4*>(&sA[c][ty * RT + 4]);
            *reinterpret_cast<float4*>(&bv[0]) =
                *reinterpret_cast<const float4*>(&sB[c][tx * CT]);
            *reinterpret_cast<float4*>(&bv[4]) =
                *reinterpret_cast<const float4*>(&sB[c][tx * CT + 4]);
#pragma unroll
            for (int r = 0; r < RT; ++r)
#pragma unroll
                for (int cc = 0; cc < CT; ++cc)
                    acc[r][cc] = __builtin_fmaf(a[r], bv[cc], acc[r][cc]);
        }
        __syncthreads();
    }

    if (EPI == 1) {
#pragma unroll
        for (int r = 0; r < RT; ++r) {
            int o = om + ty * RT + r;
            float gg = g[o], bbv = bb[o];
#pragma unroll
            for (int cc = 0; cc < CT; ++cc) {
                float v = acc[r][cc] * gg;
                v = v + bbv;
                C[(size_t)o * cols + jb + tx * CT + cc] = lrelu(v);
            }
        }
    } else if (EPI == 2) {
#pragma unroll
        for (int r = 0; r < RT; ++r) {
            int o = om + ty * RT + r;
            float gg = g[o], bbv = bb[o];
#pragma unroll
            for (int cc = 0; cc < CT; ++cc) {
                float v = acc[r][cc] * gg;
                v = v + bbv;
                C[(size_t)(jb + tx * CT + cc) * M + o] = lrelu(v);
            }
        }
    } else if (EPI == 3) {
#pragma unroll
        for (int r = 0; r < RT; ++r) {
            int o = om + ty * RT + r;
            float m = acc[r][0];
#pragma unroll
            for (int cc = 1; cc < CT; ++cc) m = fmaxf(m, acc[r][cc]);
            m = fmaxf(m, __shfl_xor(m, 1));
            float e[CT]; float ps = 0.0f;
#pragma unroll
            for (int cc = 0; cc < CT; ++cc) { e[cc] = expf(acc[r][cc] - m); ps = ps + e[cc]; }
            float tot = ps + __shfl_xor(ps, 1);
            const float* xr = B + (size_t)o * cols + jb + tx * CT;
            float pw = 0.0f;
#pragma unroll
            for (int cc = 0; cc < CT; ++cc) {
                float a_ = e[cc] / tot;
                float t = xr[cc] * a_;
                pw = pw + t;
            }
            pw = pw + __shfl_xor(pw, 1);
            if ((tx & 1) == 0)
                pooled[(size_t)o * pstride + (jb >> 4) + (tx >> 1)] = pw;
        }
    }
}

// ---------- kernel 6: candidate-parallel nearest-neighbor argmin ----------
template <int LPQ, int TS>
__launch_bounds__(256)
__global__ void k_nn_par(const float* __restrict__ tgt, const float* __restrict__ src,
                         int* __restrict__ nn, int Mt, int Ms) {
    constexpr int QPB = 256 / LPQ;
    __shared__ float sx[TS], sy[TS], sz[TS], sn[TS];
    int b = blockIdx.y;
    int tid = threadIdx.x;
    int qi = tid / LPQ;
    int l = tid % LPQ;
    int q = blockIdx.x * QPB + qi;
    const float* T = tgt + (size_t)b * Mt * 3;
    const float* S = src + (size_t)b * Ms * 3;
    float qx = T[q * 3], qy = T[q * 3 + 1], qz = T[q * 3 + 2];
    float qn = sumsq3(qx, qy, qz);
    float bd = INFINITY; int bi = 0x7fffffff;
    for (int t0 = 0; t0 < Ms; t0 += TS) {
        __syncthreads();
        for (int j = tid; j < TS; j += 256) {
            int i = t0 + j;
            float px = S[i * 3], py = S[i * 3 + 1], pz = S[i * 3 + 2];
            sx[j] = px; sy[j] = py; sz[j] = pz; sn[j] = sumsq3(px, py, pz);
        }
        __syncthreads();
        for (int j = l; j < TS; j += LPQ) {
            float d = (qn + sn[j]) - 2.0f * dot3fma(qx, qy, qz, sx[j], sy[j], sz[j]);
            if (d < bd) { bd = d; bi = t0 + j; }   // ascending idx per lane
        }
    }
#pragma unroll
    for (int s = LPQ / 2; s; s >>= 1) {
        float od = __shfl_xor(bd, s);
        int oi = __shfl_xor(bi, s);
        bool better = (od < bd) || ((od == bd) && (oi < bi));
        bd = better ? od : bd;
        bi = better ? oi : bi;
    }
    if (l == 0) nn[(size_t)b * Mt + q] = bi;
}

// ---------- kernel 7: up-sample + concat + dense + bn_act ----------
template <int CSRC, int CSKIP, int COUT>
__global__ void k_up(const float* __restrict__ srcf, const float* __restrict__ skipf,
                     const int* __restrict__ nn,
                     const float* __restrict__ W, const float* __restrict__ g, const float* __restrict__ bb,
                     float* __restrict__ outf, int Mt, int Ms) {
    __shared__ float fin[CSRC + CSKIP];
    int b = blockIdx.y, n = blockIdx.x, tid = threadIdx.x;
    int j = nn[(size_t)b * Mt + n];
    const float* fs = srcf + ((size_t)b * Ms + j) * CSRC;
    const float* fk = skipf + ((size_t)b * Mt + n) * CSKIP;
    for (int c = tid; c < CSRC; c += blockDim.x) fin[c] = fs[c];
    for (int c = tid; c < CSKIP; c += blockDim.x) fin[CSRC + c] = fk[c];
    __syncthreads();
    for (int o = tid; o < COUT; o += blockDim.x) {
        const float* wr = W + (size_t)o * (CSRC + CSKIP);
        float s = 0.0f;
        for (int c = 0; c < CSRC + CSKIP; ++c) s = __builtin_fmaf(wr[c], fin[c], s);
        float v = s * g[o]; v = v + bb[o];
        outf[((size_t)b * Mt + n) * COUT + o] = lrelu(v);
    }
}

// ---------- kernel 8: final up-sample + Wu1 + head fused ----------
__global__ void k_u1head(const float* __restrict__ srcf, const float* __restrict__ skipf,
                         const int* __restrict__ nn,
                         const float* __restrict__ Wu1, const float* __restrict__ gu1, const float* __restrict__ bu1,
                         const float* __restrict__ Wh1, const float* __restrict__ bh1,
                         const float* __restrict__ Wh2, const float* __restrict__ bh2,
                         float* __restrict__ out, int Mt, int Ms) {
    __shared__ float fin[192];
    __shared__ float d1[64];
    __shared__ float h[64];
    int b = blockIdx.y, n = blockIdx.x, tid = threadIdx.x;
    int j = nn[(size_t)b * Mt + n];
    const float* fs = srcf + ((size_t)b * Ms + j) * 128;
    const float* fk = skipf + ((size_t)b * Mt + n) * 64;
    for (int c = tid; c < 128; c += 64) fin[c] = fs[c];
    fin[128 + tid] = fk[tid];
    __syncthreads();
    {
        const float* wr = Wu1 + (size_t)tid * 192;
        float s = 0.0f;
        for (int c = 0; c < 192; ++c) s = __builtin_fmaf(wr[c], fin[c], s);
        float v = s * gu1[tid]; v = v + bu1[tid];
        d1[tid] = lrelu(v);
    }
    __syncthreads();
    {
        const float* wr = Wh1 + (size_t)tid * 64;
        float s = 0.0f;
        for (int c = 0; c < 64; ++c) s = __builtin_fmaf(wr[c], d1[c], s);
        float v = s + bh1[tid];
        h[tid] = lrelu(v);
    }
    __syncthreads();
    if (tid < 13) {
        const float* wr = Wh2 + (size_t)tid * 64;
        float s = 0.0f;
        for (int c = 0; c < 64; ++c) s = __builtin_fmaf(wr[c], h[c], s);
        out[((size_t)b * Mt + n) * 13 + tid] = s + bh2[tid];
    }
}

// ---------- launch ----------
extern "C" void kernel_launch(void* const* d_in, const int* in_sizes, int n_in,
                              void* d_out, int out_size, void* d_ws, size_t ws_size,
                              hipStream_t stream) {
    const float* xyz  = (const float*)d_in[0];
    const float* feat = (const float*)d_in[1];
    const int*   sel1 = (const int*)d_in[2];
    const int*   sel2 = (const int*)d_in[3];
    const float* Wpre = (const float*)d_in[4];
    const float* gpre = (const float*)d_in[5];
    const float* bpre = (const float*)d_in[6];
    const float* W1m  = (const float*)d_in[7];
    const float* g1m  = (const float*)d_in[8];
    const float* b1m  = (const float*)d_in[9];
    const float* W1s  = (const float*)d_in[10];
    const float* W1p  = (const float*)d_in[11];
    const float* g1p  = (const float*)d_in[12];
    const float* b1p  = (const float*)d_in[13];
    const float* W2m  = (const float*)d_in[14];
    const float* g2m  = (const float*)d_in[15];
    const float* b2m  = (const float*)d_in[16];
    const float* W2s  = (const float*)d_in[17];
    const float* W2p  = (const float*)d_in[18];
    const float* g2p  = (const float*)d_in[19];
    const float* b2p  = (const float*)d_in[20];
    const float* W3m  = (const float*)d_in[21];
    const float* g3m  = (const float*)d_in[22];
    const float* b3m  = (const float*)d_in[23];
    const float* W3s  = (const float*)d_in[24];
    const float* W3p  = (const float*)d_in[25];
    const float* g3p  = (const float*)d_in[26];
    const float* b3p  = (const float*)d_in[27];
    const float* Wu2  = (const float*)d_in[28];
    const float* gu2  = (const float*)d_in[29];
    const float* bu2  = (const float*)d_in[30];
    const float* Wu1  = (const float*)d_in[31];
    const float* gu1  = (const float*)d_in[32];
    const float* bu1  = (const float*)d_in[33];
    const float* Wh1  = (const float*)d_in[34];
    const float* bh1  = (const float*)d_in[35];
    const float* Wh2  = (const float*)d_in[36];
    const float* bh2  = (const float*)d_in[37];
    float* out = (float*)d_out;

    char* w = (char*)d_ws;
    auto alloc = [&](size_t n) { char* p = w; w += (n + 255) & ~(size_t)255; return p; };
    float* x0   = (float*)alloc((size_t)2 * 8192 * 64 * 4);
    float* x1   = (float*)alloc((size_t)2 * 8192 * 64 * 4);
    float* f1   = (float*)alloc((size_t)2 * 4096 * 64 * 4);
    float* x2   = (float*)alloc((size_t)2 * 4096 * 128 * 4);
    float* f2   = (float*)alloc((size_t)2 * 2048 * 128 * 4);
    float* x3   = (float*)alloc((size_t)2 * 2048 * 256 * 4);
    float* d2f  = (float*)alloc((size_t)2 * 4096 * 128 * 4);
    float* xyz1 = (float*)alloc((size_t)2 * 4096 * 3 * 4);
    float* xyz2 = (float*)alloc((size_t)2 * 2048 * 3 * 4);
    int* n0   = (int*)alloc((size_t)2 * 8192 * 16 * 4);
    int* n1   = (int*)alloc((size_t)2 * 4096 * 16 * 4);
    int* n2   = (int*)alloc((size_t)2 * 2048 * 16 * 4);
    int* nnu2 = (int*)alloc((size_t)2 * 4096 * 4);
    int* nnu1 = (int*)alloc((size_t)2 * 8192 * 4);
    float* XIN  = (float*)alloc((size_t)74 * 65536 * 4);
    float* XMID = (float*)alloc((size_t)64 * 65536 * 4);
    float* pooled = (float*)alloc((size_t)64 * 16384 * 4);

    k_pre<<<128, 128, 0, stream>>>(feat, Wpre, gpre, bpre, x0);

    // ---- level 1 ----
    k_knn_reg<32, 512><<<dim3(1024, 2), 256, 0, stream>>>(xyz, n0, 8192);
    {
        const int cols = 2 * 8192 * 16, chunk = cols / 4;
        for (int s = 0; s < 4; ++s) {
            int j0 = s * chunk;
            k_encode<64><<<chunk / 256, 256, 0, stream>>>(xyz, x0, n0, XIN, 8192, chunk, j0);
            k_gemm<64, 128, 16, 1><<<dim3(chunk / 128, 1), 256, 0, stream>>>(
                W1m, XIN, g1m, b1m, XMID, nullptr, 64, 74, chunk, 0);
            k_gemm<64, 128, 16, 3><<<dim3(chunk / 128, 1), 256, 0, stream>>>(
                W1s, XMID, nullptr, nullptr, nullptr, pooled + j0 / 16, 64, 64, chunk, cols / 16);
        }
        k_gemm<64, 128, 16, 2><<<dim3(16384 / 128, 1), 256, 0, stream>>>(
            W1p, pooled, g1p, b1p, x1, nullptr, 64, 64, 16384, 0);
    }

    // ---- level 2 ----
    k_gather<64><<<dim3(4096, 2), 64, 0, stream>>>(xyz, x1, sel1, xyz1, f1, 4096, 8192);
    k_knn_reg<32, 512><<<dim3(512, 2), 256, 0, stream>>>(xyz1, n1, 4096);
    {
        const int cols = 2 * 4096 * 16, chunk = cols / 4;
        for (int s = 0; s < 4; ++s) {
            int j0 = s * chunk;
            k_encode<64><<<chunk / 256, 256, 0, stream>>>(xyz1, f1, n1, XIN, 4096, chunk, j0);
            k_gemm<128, 128, 16, 1><<<dim3(chunk / 128, 1), 256, 0, stream>>>(
                W2m, XIN, g2m, b2m, XMID, nullptr, 128, 74, chunk, 0);
            k_gemm<128, 128, 16, 3><<<dim3(chunk / 128, 1), 256, 0, stream>>>(
                W2s, XMID, nullptr, nullptr, nullptr, pooled + j0 / 16, 128, 128, chunk, cols / 16);
        }
        k_gemm<128, 128, 16, 2><<<dim3(8192 / 128, 1), 256, 0, stream>>>(
            W2p, pooled, g2p, b2p, x2, nullptr, 128, 128, 8192, 0);
    }

    // ---- level 3 ----
    k_gather<128><<<dim3(2048, 2), 64, 0, stream>>>(xyz1, x2, sel2, xyz2, f2, 2048, 4096);
    k_knn_reg<32, 512><<<dim3(256, 2), 256, 0, stream>>>(xyz2, n2, 2048);
    {
        const int cols = 2 * 2048 * 16, chunk = cols / 4;
        for (int s = 0; s < 4; ++s) {
            int j0 = s * chunk;
            k_encode<128><<<chunk / 256, 256, 0, stream>>>(xyz2, f2, n2, XIN, 2048, chunk, j0);
            k_gemm<128, 128, 16, 1><<<dim3(chunk / 128, 2), 256, 0, stream>>>(
                W3m, XIN, g3m, b3m, XMID, nullptr, 256, 138, chunk, 0);
            k_gemm<128, 128, 16, 3><<<dim3(chunk / 128, 2), 256, 0, stream>>>(
                W3s, XMID, nullptr, nullptr, nullptr, pooled + j0 / 16, 256, 256, chunk, cols / 16);
        }
        k_gemm<128, 128, 16, 2><<<dim3(4096 / 128, 2), 256, 0, stream>>>(
            W3p, pooled, g3p, b3p, x3, nullptr, 256, 256, 4096, 0);
    }

    // ---- decoder ----
    k_nn_par<16, 512><<<dim3(256, 2), 256, 0, stream>>>(xyz1, xyz2, nnu2, 4096, 2048);
    k_up<256, 128, 128><<<dim3(4096, 2), 128, 0, stream>>>(x3, x2, nnu2, Wu2, gu2, bu2,
                                                           d2f, 4096, 2048);
    k_nn_par<16, 512><<<dim3(512, 2), 256, 0, stream>>>(xyz, xyz1, nnu1, 8192, 4096);
    k_u1head<<<dim3(8192, 2), 64, 0, stream>>>(d2f, x1, nnu1, Wu1, gu1, bu1, Wh1, bh1,
                                               Wh2, bh2, out, 8192, 4096);
}